// Round 1
// baseline (218.434 us; speedup 1.0000x reference)
//
#include <hip/hip_runtime.h>
#include <math.h>

namespace {

constexpr int CIN  = 64;
constexpr int COUT = 128;
constexpr int LEN  = 4096;
constexpr int LH   = 2048;   // LEN/2
constexpr int NT   = 256;
constexpr float INV_SQRT2 = 0.70710678118654752440f;

// One block handles one (n, ic) pair: loads x row once, produces output
// channels oc = 2*ic and 2*ic+1 (the two channels of conv group ic).
__global__ __launch_bounds__(NT) void fused_wavelet_kernel(
    const float* __restrict__ x,
    const float* __restrict__ w1,
    const float* __restrict__ g1,
    const float* __restrict__ b1,
    const float* __restrict__ m1,
    const float* __restrict__ v1,
    const float* __restrict__ w2L,
    const float* __restrict__ w2H,
    const float* __restrict__ wskip,
    float* __restrict__ out)
{
    // Halo-padded LDS buffers; halos hold zeros => branch-free zero padding.
    __shared__ float sx[LEN + 8];  // valid data at [4, 4+LEN); need +/-3 halo
    __shared__ float sh[LEN];      // h = leaky(gelu(bn(conv7(x))))
    __shared__ float sL[LH + 8];   // xL0 at [4, 4+LH); need +/-3 halo
    __shared__ float sH[LH + 4];   // xH0 at [2, 2+LH); need +/-1 halo

    const int tid = threadIdx.x;
    const int n   = blockIdx.x >> 6;   // / CIN
    const int ic  = blockIdx.x & 63;   // % CIN

    // Zero the halos (stay zero across both oc iterations).
    if (tid < 4) {
        sx[tid] = 0.f; sx[LEN + 4 + tid] = 0.f;
        sL[tid] = 0.f; sL[LH + 4 + tid] = 0.f;
    }
    if (tid < 2) {
        sH[tid] = 0.f; sH[LH + 2 + tid] = 0.f;
    }

    // Coalesced float4 load of the x row into LDS.
    const float4* xrow = (const float4*)(x + (size_t)(n * CIN + ic) * LEN);
    float4* sx4 = (float4*)(sx + 4);   // 16B-aligned (offset 4 floats)
    #pragma unroll
    for (int i = 0; i < LEN / 4 / NT; ++i)
        sx4[tid + i * NT] = xrow[tid + i * NT];
    __syncthreads();

    #pragma unroll
    for (int j = 0; j < 2; ++j) {
        const int oc = 2 * ic + j;

        // --- Stage A: h = leaky(gelu(bn(conv7(x)))) ---
        float wc[7];
        #pragma unroll
        for (int k = 0; k < 7; ++k) wc[k] = w1[oc * 7 + k];
        const float inv   = g1[oc] * rsqrtf(v1[oc] + 1e-5f);
        const float shift = b1[oc] - m1[oc] * inv;

        #pragma unroll
        for (int i = 0; i < LEN / NT; ++i) {
            const int l = tid + i * NT;
            const float* p = sx + 1 + l;   // sx[4 + (l-3)]
            float acc = p[0] * wc[0];
            acc = fmaf(p[1], wc[1], acc);
            acc = fmaf(p[2], wc[2], acc);
            acc = fmaf(p[3], wc[3], acc);
            acc = fmaf(p[4], wc[4], acc);
            acc = fmaf(p[5], wc[5], acc);
            acc = fmaf(p[6], wc[6], acc);
            float t = fmaf(acc, inv, shift);
            // exact GELU: 0.5*t*(1+erf(t/sqrt(2)))
            float g = 0.5f * t * (1.0f + erff(t * INV_SQRT2));
            sh[l] = (g >= 0.f) ? g : 0.01f * g;   // leaky relu
        }
        __syncthreads();

        // --- Stage B: Haar analysis ---
        const float2* sh2 = (const float2*)sh;
        #pragma unroll
        for (int i = 0; i < LH / NT; ++i) {
            const int t = tid + i * NT;
            const float2 eo = sh2[t];                  // h[2t], h[2t+1]
            sL[t + 4] = (eo.x + eo.y) * INV_SQRT2;
            sH[t + 2] = (eo.x - eo.y) * INV_SQRT2;
        }
        __syncthreads();

        // --- Stage C: stencils + inverse Haar + skip + leaky, store ---
        float wl[7], wh[3];
        #pragma unroll
        for (int k = 0; k < 7; ++k) wl[k] = w2L[oc * 7 + k];
        #pragma unroll
        for (int k = 0; k < 3; ++k) wh[k] = w2H[oc * 3 + k];
        const float ws = wskip[oc];

        float2* orow = (float2*)(out + (size_t)(n * COUT + oc) * LEN);
        const float2* sx2 = (const float2*)(sx + 4);

        #pragma unroll
        for (int i = 0; i < LH / NT; ++i) {
            const int t = tid + i * NT;
            // xL[t] = sum_k xL0[t-3+k]*wl[k]  (sL index t-3+k+4 = t+1+k)
            float xl = sL[t + 1] * wl[0];
            xl = fmaf(sL[t + 2], wl[1], xl);
            xl = fmaf(sL[t + 3], wl[2], xl);
            xl = fmaf(sL[t + 4], wl[3], xl);
            xl = fmaf(sL[t + 5], wl[4], xl);
            xl = fmaf(sL[t + 6], wl[5], xl);
            xl = fmaf(sL[t + 7], wl[6], xl);
            // xH[t] = sum_k xH0[t-1+k]*wh[k]  (sH index t-1+k+2 = t+1+k)
            float xh = sH[t + 1] * wh[0];
            xh = fmaf(sH[t + 2], wh[1], xh);
            xh = fmaf(sH[t + 3], wh[2], xh);

            const float re = (xl + xh) * INV_SQRT2;
            const float ro = (xl - xh) * INV_SQRT2;

            const float2 xv = sx2[t];   // x[2t], x[2t+1]
            float oe = fmaf(xv.x, ws, re);
            float oo = fmaf(xv.y, ws, ro);
            oe = (oe >= 0.f) ? oe : 0.01f * oe;
            oo = (oo >= 0.f) ? oo : 0.01f * oo;
            orow[t] = make_float2(oe, oo);
        }
        // No trailing sync needed: next iteration's Stage A only writes sh,
        // which Stage C never reads; the sync after Stage A separates this
        // Stage C's sL/sH reads from the next Stage B's writes.
        if (j == 0) __syncthreads();  // cheap safety barrier between channels
    }
}

} // namespace

extern "C" void kernel_launch(void* const* d_in, const int* in_sizes, int n_in,
                              void* d_out, int out_size, void* d_ws, size_t ws_size,
                              hipStream_t stream) {
    const float* x    = (const float*)d_in[0];
    const float* w1   = (const float*)d_in[1];
    const float* g1   = (const float*)d_in[2];
    const float* b1   = (const float*)d_in[3];
    const float* m1   = (const float*)d_in[4];
    const float* v1   = (const float*)d_in[5];
    const float* w2L  = (const float*)d_in[6];
    const float* w2H  = (const float*)d_in[7];
    const float* wsk  = (const float*)d_in[8];
    float* out = (float*)d_out;

    const int Bn = in_sizes[0] / (CIN * LEN);   // batch = 64
    fused_wavelet_kernel<<<dim3(Bn * CIN), dim3(NT), 0, stream>>>(
        x, w1, g1, b1, m1, v1, w2L, w2H, wsk, out);
}

// Round 2
// 201.338 us; speedup vs baseline: 1.0849x; 1.0849x over previous
//
#include <hip/hip_runtime.h>
#include <math.h>

namespace {

constexpr int CIN  = 64;
constexpr int COUT = 128;
constexpr int LEN  = 4096;
constexpr int LH   = 2048;   // LEN/2
constexpr int NT   = 512;
constexpr float INV_SQRT2 = 0.70710678118654752440f;

// Fast exact-enough GELU: tanh form, computed as t*e/(e+1) with e=exp(...).
// Max abs error vs erf-exact GELU ~1e-3 (threshold slack is 20x that after
// conv2 amplification). Handles +/-inf limits correctly (e=inf -> g=t; e=0 -> g=0).
__device__ __forceinline__ float gelu_fast(float t) {
    float t3 = t * t * t;
    float y  = 1.5957691216057308f * fmaf(0.044715f, t3, t);  // 2*0.7978845608*(t+0.044715 t^3)
    float e  = __expf(y);                                      // v_exp_f32 + mul
    float d  = __builtin_amdgcn_rcpf(e + 1.0f);                // v_rcp_f32
    return t - t * d;                                          // t*e/(e+1)
}

// One block per (n, ic): loads the x row once into LDS, produces output
// channels oc = 2*ic and 2*ic+1. Stage A (conv7+bn+gelu+leaky) and Stage B
// (Haar analysis) are fused: each thread computes the h-pair for position t
// in registers and writes xL0/xH0 straight to LDS (no sh round-trip).
__global__ __launch_bounds__(NT, 8) void fused_wavelet_kernel(
    const float* __restrict__ x,
    const float* __restrict__ w1,
    const float* __restrict__ g1,
    const float* __restrict__ b1,
    const float* __restrict__ m1,
    const float* __restrict__ v1,
    const float* __restrict__ w2L,
    const float* __restrict__ w2H,
    const float* __restrict__ wskip,
    float* __restrict__ out)
{
    // Halo-padded LDS; halos hold zeros => branch-free zero padding.
    __shared__ float sx[LEN + 8];  // x row at [4, 4+LEN); +/-3 halo used
    __shared__ float sL[LH + 8];   // xL0 at [4, 4+LH); +/-3 halo
    __shared__ float sH[LH + 4];   // xH0 at [2, 2+LH); +/-1 halo
    // Total: (4104 + 2056 + 2052)*4 = 32848 B -> 4 blocks/CU, 32 waves/CU.

    const int tid = threadIdx.x;
    const int n   = blockIdx.x >> 6;   // / CIN
    const int ic  = blockIdx.x & 63;   // % CIN

    if (tid < 4) {
        sx[tid] = 0.f; sx[LEN + 4 + tid] = 0.f;
        sL[tid] = 0.f; sL[LH + 4 + tid] = 0.f;
    }
    if (tid < 2) {
        sH[tid] = 0.f; sH[LH + 2 + tid] = 0.f;
    }

    // Coalesced float4 load of the x row into LDS.
    const float4* xrow = (const float4*)(x + (size_t)(n * CIN + ic) * LEN);
    float4* sx4 = (float4*)(sx + 4);   // 16B-aligned (offset = 4 floats)
    #pragma unroll
    for (int i = 0; i < LEN / 4 / NT; ++i)
        sx4[tid + i * NT] = xrow[tid + i * NT];
    __syncthreads();

    const float2* sxp = (const float2*)sx;        // sxp[t] = {sx[2t], sx[2t+1]}
    const float2* sx2 = (const float2*)(sx + 4);  // data pairs for the skip path

    for (int j = 0; j < 2; ++j) {
        const int oc = 2 * ic + j;

        // --- Stage A+B fused: h pair -> Haar coefficients ---
        float wc[7];
        #pragma unroll
        for (int k = 0; k < 7; ++k) wc[k] = w1[oc * 7 + k];
        const float inv   = g1[oc] * rsqrtf(v1[oc] + 1e-5f);
        const float shift = b1[oc] - m1[oc] * inv;

        #pragma unroll
        for (int i = 0; i < LH / NT; ++i) {
            const int t = tid + i * NT;
            // Need p[k] = sx[2t+k] for k=1..8 (h[2t] uses p1..p7, h[2t+1] p2..p8).
            const float2 q0 = sxp[t];
            const float2 q1 = sxp[t + 1];
            const float2 q2 = sxp[t + 2];
            const float2 q3 = sxp[t + 3];
            const float2 q4 = sxp[t + 4];
            const float p1 = q0.y, p2 = q1.x, p3 = q1.y, p4 = q2.x,
                        p5 = q2.y, p6 = q3.x, p7 = q3.y, p8 = q4.x;

            float ae = p1 * wc[0];
            ae = fmaf(p2, wc[1], ae); ae = fmaf(p3, wc[2], ae);
            ae = fmaf(p4, wc[3], ae); ae = fmaf(p5, wc[4], ae);
            ae = fmaf(p6, wc[5], ae); ae = fmaf(p7, wc[6], ae);
            float ao = p2 * wc[0];
            ao = fmaf(p3, wc[1], ao); ao = fmaf(p4, wc[2], ao);
            ao = fmaf(p5, wc[3], ao); ao = fmaf(p6, wc[4], ao);
            ao = fmaf(p7, wc[5], ao); ao = fmaf(p8, wc[6], ao);

            const float te = fmaf(ae, inv, shift);
            const float to = fmaf(ao, inv, shift);
            float ge = gelu_fast(te);
            float go = gelu_fast(to);
            ge = fmaxf(ge, 0.01f * ge);   // leaky relu, branchless
            go = fmaxf(go, 0.01f * go);

            sL[t + 4] = (ge + go) * INV_SQRT2;
            sH[t + 2] = (ge - go) * INV_SQRT2;
        }
        __syncthreads();

        // --- Stage C: conv7(xL) + conv3(xH) -> inverse Haar + skip + leaky ---
        float wl[7], wh[3];
        #pragma unroll
        for (int k = 0; k < 7; ++k) wl[k] = w2L[oc * 7 + k];
        #pragma unroll
        for (int k = 0; k < 3; ++k) wh[k] = w2H[oc * 3 + k];
        const float ws = wskip[oc];

        float2* orow = (float2*)(out + (size_t)(n * COUT + oc) * LEN);

        #pragma unroll
        for (int i = 0; i < LH / NT; ++i) {
            const int t = tid + i * NT;
            float xl = sL[t + 1] * wl[0];
            xl = fmaf(sL[t + 2], wl[1], xl);
            xl = fmaf(sL[t + 3], wl[2], xl);
            xl = fmaf(sL[t + 4], wl[3], xl);
            xl = fmaf(sL[t + 5], wl[4], xl);
            xl = fmaf(sL[t + 6], wl[5], xl);
            xl = fmaf(sL[t + 7], wl[6], xl);
            float xh = sH[t + 1] * wh[0];
            xh = fmaf(sH[t + 2], wh[1], xh);
            xh = fmaf(sH[t + 3], wh[2], xh);

            const float re = (xl + xh) * INV_SQRT2;
            const float ro = (xl - xh) * INV_SQRT2;

            const float2 xv = sx2[t];
            float oe = fmaf(xv.x, ws, re);
            float oo = fmaf(xv.y, ws, ro);
            oe = fmaxf(oe, 0.01f * oe);
            oo = fmaxf(oo, 0.01f * oo);
            orow[t] = make_float2(oe, oo);
        }
        // WAR barrier: next channel's Stage A+B rewrites sL/sH that this
        // Stage C just read.
        if (j == 0) __syncthreads();
    }
}

} // namespace

extern "C" void kernel_launch(void* const* d_in, const int* in_sizes, int n_in,
                              void* d_out, int out_size, void* d_ws, size_t ws_size,
                              hipStream_t stream) {
    const float* x    = (const float*)d_in[0];
    const float* w1   = (const float*)d_in[1];
    const float* g1   = (const float*)d_in[2];
    const float* b1   = (const float*)d_in[3];
    const float* m1   = (const float*)d_in[4];
    const float* v1   = (const float*)d_in[5];
    const float* w2L  = (const float*)d_in[6];
    const float* w2H  = (const float*)d_in[7];
    const float* wsk  = (const float*)d_in[8];
    float* out = (float*)d_out;

    const int Bn = in_sizes[0] / (CIN * LEN);   // batch = 64
    fused_wavelet_kernel<<<dim3(Bn * CIN), dim3(NT), 0, stream>>>(
        x, w1, g1, b1, m1, v1, w2L, w2H, wsk, out);
}

// Round 3
// 196.872 us; speedup vs baseline: 1.1095x; 1.0227x over previous
//
#include <hip/hip_runtime.h>
#include <math.h>

namespace {

constexpr int CIN  = 64;
constexpr int COUT = 128;
constexpr int LEN  = 4096;
constexpr int LH   = 2048;   // LEN/2
constexpr int NT   = 512;
constexpr float INV_SQRT2 = 0.70710678118654752440f;

// Fast exact-enough GELU (tanh form as t*e/(e+1)). Max abs err ~1e-3 vs
// erf-exact; measured end-to-end absmax 0.0156 vs 0.0753 threshold (R2).
__device__ __forceinline__ float gelu_fast(float t) {
    float t3 = t * t * t;
    float y  = 1.5957691216057308f * fmaf(0.044715f, t3, t);
    float e  = __expf(y);
    float d  = __builtin_amdgcn_rcpf(e + 1.0f);
    return t - t * d;   // t*e/(e+1); correct limits at +/-inf
}

// One block per (n, ic). x row stored DEINTERLEAVED in LDS (even/odd) so the
// pair-structured stencils read aligned float4 blocks (conflict-free b128).
// Thread coarsening x4: thread handles tau/t = 4*tid..4*tid+3; all LDS ops
// are b128 at lane-stride 16B (contiguous -> conflict-free).
// Physical layouts (all zero-padded halos):
//   sxe[p] = x[2*(p-2)]   : xe[k] at p=k+2, writes p=2..2049, zeros 0,1,2050+
//   sxo[p] = x[2*(p-2)+1] : same
//   sL[p]  = xL0[p-4]     : writes p=4..2051, zeros 0..3, 2052..2055
//   sH[p]  = xH0[p-4]     : same
__global__ __launch_bounds__(NT, 4) void fused_wavelet_kernel(
    const float* __restrict__ x,
    const float* __restrict__ w1,
    const float* __restrict__ g1,
    const float* __restrict__ b1,
    const float* __restrict__ m1,
    const float* __restrict__ v1,
    const float* __restrict__ w2L,
    const float* __restrict__ w2H,
    const float* __restrict__ wskip,
    float* __restrict__ out)
{
    __shared__ float sxe[2056];
    __shared__ float sxo[2056];
    __shared__ float sL[2056];
    __shared__ float sH[2056];
    // 4*2056*4 = 32896 B

    const int tid = threadIdx.x;
    const int n   = blockIdx.x >> 6;   // / CIN
    const int ic  = blockIdx.x & 63;   // % CIN

    // Zero only never-written halo entries (no race with the loader).
    if (tid < 8) {
        int jx = (tid < 2) ? tid : (2048 + tid);   // 0,1,2050..2055
        sxe[jx] = 0.f; sxo[jx] = 0.f;
        int jl = (tid < 4) ? tid : (2048 + tid);   // 0..3,2052..2055
        sL[jl] = 0.f; sH[jl] = 0.f;
    }

    // Coalesced float4 global load, deinterleave into sxe/sxo via b64 writes.
    const float4* xrow4 = (const float4*)(x + (size_t)(n * CIN + ic) * LEN);
    #pragma unroll
    for (int i = 0; i < 2; ++i) {
        const int k = tid + i * NT;        // float4 index: x[4k..4k+3] = pairs 2k,2k+1
        const float4 v = xrow4[k];
        *(float2*)(sxe + 2 * k + 2) = make_float2(v.x, v.z);
        *(float2*)(sxo + 2 * k + 2) = make_float2(v.y, v.w);
    }
    __syncthreads();

    // Persistent per-thread x blocks: phys 4*tid..4*tid+7 of each array.
    // E[j] = sxe[4*tid+j] = xe[4*tid+j-2]; O[j] likewise for xo.
    float E[8], O[8];
    {
        const float4* sxe4 = (const float4*)sxe;
        const float4* sxo4 = (const float4*)sxo;
        const float4 e0 = sxe4[tid], e1 = sxe4[tid + 1];
        const float4 o0 = sxo4[tid], o1 = sxo4[tid + 1];
        E[0]=e0.x; E[1]=e0.y; E[2]=e0.z; E[3]=e0.w;
        E[4]=e1.x; E[5]=e1.y; E[6]=e1.z; E[7]=e1.w;
        O[0]=o0.x; O[1]=o0.y; O[2]=o0.z; O[3]=o0.w;
        O[4]=o1.x; O[5]=o1.y; O[6]=o1.z; O[7]=o1.w;
    }
    // For tau = 4*tid+s:  xe[tau-1+i] = E[1+s+i],  xo[tau-2+i] = O[s+i].

    for (int j = 0; j < 2; ++j) {
        const int oc = 2 * ic + j;

        // --- Stage A+B: conv7+bn+gelu+leaky on pairs -> Haar coeffs ---
        float wc[7];
        #pragma unroll
        for (int k = 0; k < 7; ++k) wc[k] = w1[oc * 7 + k];
        const float inv   = g1[oc] * rsqrtf(v1[oc] + 1e-5f);
        const float shift = b1[oc] - m1[oc] * inv;

        float Lw[4], Hw[4];
        #pragma unroll
        for (int s = 0; s < 4; ++s) {
            // h[2*tau]:  xo[t-2]w0 xe[t-1]w1 xo[t-1]w2 xe[t]w3 xo[t]w4 xe[t+1]w5 xo[t+1]w6
            float he = O[s] * wc[0];
            he = fmaf(E[1 + s], wc[1], he);
            he = fmaf(O[s + 1], wc[2], he);
            he = fmaf(E[2 + s], wc[3], he);
            he = fmaf(O[s + 2], wc[4], he);
            he = fmaf(E[3 + s], wc[5], he);
            he = fmaf(O[s + 3], wc[6], he);
            // h[2*tau+1]: xe[t-1]w0 xo[t-1]w1 xe[t]w2 xo[t]w3 xe[t+1]w4 xo[t+1]w5 xe[t+2]w6
            float ho = E[1 + s] * wc[0];
            ho = fmaf(O[s + 1], wc[1], ho);
            ho = fmaf(E[2 + s], wc[2], ho);
            ho = fmaf(O[s + 2], wc[3], ho);
            ho = fmaf(E[3 + s], wc[4], ho);
            ho = fmaf(O[s + 3], wc[5], ho);
            ho = fmaf(E[4 + s], wc[6], ho);

            const float te = fmaf(he, inv, shift);
            const float to = fmaf(ho, inv, shift);
            float ge = gelu_fast(te);
            float go = gelu_fast(to);
            ge = fmaxf(ge, 0.01f * ge);
            go = fmaxf(go, 0.01f * go);

            Lw[s] = (ge + go) * INV_SQRT2;
            Hw[s] = (ge - go) * INV_SQRT2;
        }
        ((float4*)sL)[tid + 1] = make_float4(Lw[0], Lw[1], Lw[2], Lw[3]);
        ((float4*)sH)[tid + 1] = make_float4(Hw[0], Hw[1], Hw[2], Hw[3]);
        __syncthreads();

        // --- Stage C: conv7(xL0)+conv3(xH0) -> inverse Haar + skip + leaky ---
        float wl[7], wh[3];
        #pragma unroll
        for (int k = 0; k < 7; ++k) wl[k] = w2L[oc * 7 + k];
        #pragma unroll
        for (int k = 0; k < 3; ++k) wh[k] = w2H[oc * 3 + k];
        const float ws = wskip[oc];

        // Lb[i] = sL[4*tid+i], Hb[i] = sH[4*tid+i], i=0..11 (3 aligned b128 each).
        float Lb[12], Hb[12];
        {
            const float4* sL4 = (const float4*)sL;
            const float4* sH4 = (const float4*)sH;
            const float4 p0 = sL4[tid], p1 = sL4[tid + 1], p2 = sL4[tid + 2];
            const float4 q0 = sH4[tid], q1 = sH4[tid + 1], q2 = sH4[tid + 2];
            Lb[0]=p0.x; Lb[1]=p0.y; Lb[2]=p0.z; Lb[3]=p0.w;
            Lb[4]=p1.x; Lb[5]=p1.y; Lb[6]=p1.z; Lb[7]=p1.w;
            Lb[8]=p2.x; Lb[9]=p2.y; Lb[10]=p2.z; Lb[11]=p2.w;
            Hb[0]=q0.x; Hb[1]=q0.y; Hb[2]=q0.z; Hb[3]=q0.w;
            Hb[4]=q1.x; Hb[5]=q1.y; Hb[6]=q1.z; Hb[7]=q1.w;
            Hb[8]=q2.x; Hb[9]=q2.y; Hb[10]=q2.z; Hb[11]=q2.w;
        }
        // xL0[t0-3+i] = Lb[1+i], xH0[t0-3+i] = Hb[1+i]  (t0 = 4*tid)

        float res[8];
        #pragma unroll
        for (int s = 0; s < 4; ++s) {
            // xl = sum_k xL0[t-3+k]*wl[k] = sum_k Lb[1+s+k]*wl[k]
            float xl = Lb[1 + s] * wl[0];
            xl = fmaf(Lb[2 + s], wl[1], xl);
            xl = fmaf(Lb[3 + s], wl[2], xl);
            xl = fmaf(Lb[4 + s], wl[3], xl);
            xl = fmaf(Lb[5 + s], wl[4], xl);
            xl = fmaf(Lb[6 + s], wl[5], xl);
            xl = fmaf(Lb[7 + s], wl[6], xl);
            // xh = sum_k xH0[t-1+k]*wh[k] = sum_k Hb[3+s+k]*wh[k]
            float xh = Hb[3 + s] * wh[0];
            xh = fmaf(Hb[4 + s], wh[1], xh);
            xh = fmaf(Hb[5 + s], wh[2], xh);

            const float re = (xl + xh) * INV_SQRT2;
            const float ro = (xl - xh) * INV_SQRT2;

            // skip: x[2t] = xe[t0+s] = E[2+s], x[2t+1] = xo[t0+s] = O[2+s]
            float oe = fmaf(E[2 + s], ws, re);
            float oo = fmaf(O[2 + s], ws, ro);
            oe = fmaxf(oe, 0.01f * oe);
            oo = fmaxf(oo, 0.01f * oo);
            res[2 * s]     = oe;
            res[2 * s + 1] = oo;
        }

        float4* orow4 = (float4*)(out + (size_t)(n * COUT + oc) * LEN);
        orow4[2 * tid]     = make_float4(res[0], res[1], res[2], res[3]);
        orow4[2 * tid + 1] = make_float4(res[4], res[5], res[6], res[7]);

        // WAR barrier: channel 1's Stage B rewrites sL/sH just read here.
        if (j == 0) __syncthreads();
    }
}

} // namespace

extern "C" void kernel_launch(void* const* d_in, const int* in_sizes, int n_in,
                              void* d_out, int out_size, void* d_ws, size_t ws_size,
                              hipStream_t stream) {
    const float* x    = (const float*)d_in[0];
    const float* w1   = (const float*)d_in[1];
    const float* g1   = (const float*)d_in[2];
    const float* b1   = (const float*)d_in[3];
    const float* m1   = (const float*)d_in[4];
    const float* v1   = (const float*)d_in[5];
    const float* w2L  = (const float*)d_in[6];
    const float* w2H  = (const float*)d_in[7];
    const float* wsk  = (const float*)d_in[8];
    float* out = (float*)d_out;

    const int Bn = in_sizes[0] / (CIN * LEN);   // batch = 64
    fused_wavelet_kernel<<<dim3(Bn * CIN), dim3(NT), 0, stream>>>(
        x, w1, g1, b1, m1, v1, w2L, w2H, wsk, out);
}